// Round 3
// baseline (236.291 us; speedup 1.0000x reference)
//
#include <hip/hip_runtime.h>

// Forward-fill imputation (SIMPLE.imputate), two-kernel MLP-optimized version.
//   observed = mask < 0.9
//   gather_idx[b,n] = most recent observed pos <= n (wrap-around to row's last
//                     observed for leading missing; 0 if row has none)
//   out[b,n,:] = in[b, gather_idx[b,n], :]
//
// B=64, N=4096, D=128 fp32. Memory-bound; round-2 fused kernel was
// LATENCY-bound (2.4 TB/s, VGPR=32 -> no loads in flight). This version:
// scan kernel writes gidx to d_ws; gather kernel batches 8 independent
// float4 loads per thread (indices preloaded to registers), no LDS/barriers,
// nontemporal stores so the output stream doesn't evict input from L3.

#define FF_N 4096
#define FF_D 128

typedef float f4 __attribute__((ext_vector_type(4)));

// ---------- Phase 1: per-row forward-fill scan ----------
// One block (256 thr) per batch row; 16 elems/thread; shfl-based wave scan +
// one barrier to combine the 4 wave maxima.
__global__ __launch_bounds__(256) void ffill_scan(const float* __restrict__ mask,
                                                  int* __restrict__ gidx) {
    const int b = blockIdx.x;
    const float* m = mask + (size_t)b * FF_N;
    int* g = gidx + (size_t)b * FF_N;
    const int tid  = threadIdx.x;
    const int base = tid * 16;

    float4 mv[4];
    const float4* m4 = reinterpret_cast<const float4*>(m + base);
#pragma unroll
    for (int k = 0; k < 4; ++k) mv[k] = m4[k];

    unsigned obsbits = 0;
    int segmax = -1;
#pragma unroll
    for (int k = 0; k < 4; ++k) {
        const float vals[4] = {mv[k].x, mv[k].y, mv[k].z, mv[k].w};
#pragma unroll
        for (int j = 0; j < 4; ++j) {
            const int idx = k * 4 + j;
            const bool o = vals[j] < 0.9f;     // observed
            obsbits |= (unsigned)o << idx;
            if (o) segmax = base + idx;
        }
    }

    // Wave-level inclusive max-scan of per-thread segment maxima (no barriers).
    const int lane = tid & 63;
    int incl = segmax;
#pragma unroll
    for (int off = 1; off < 64; off <<= 1) {
        const int t = __shfl_up(incl, off, 64);
        if (lane >= off) incl = max(incl, t);
    }

    // Combine the 4 waves via LDS (single barrier).
    __shared__ int wmax[4];
    if (lane == 63) wmax[tid >> 6] = incl;
    __syncthreads();
    const int wid = tid >> 6;
    int wpre = -1, total = -1;
#pragma unroll
    for (int w = 0; w < 4; ++w) {
        const int x = wmax[w];
        total = max(total, x);
        if (w < wid) wpre = max(wpre, x);
    }
    const int inclp  = __shfl_up(incl, 1, 64);
    const int prefix = max(wpre, (lane == 0) ? -1 : inclp);  // excl. prefix
    const int fallback = (total < 0) ? 0 : total;            // empty row -> 0

    // Serial forward fill within my 16 elements.
    int last = prefix;
    int outv[16];
#pragma unroll
    for (int k = 0; k < 16; ++k) {
        if ((obsbits >> k) & 1u) last = base + k;
        outv[k] = (last < 0) ? fallback : last;
    }
    int4* g4 = reinterpret_cast<int4*>(g + base);
#pragma unroll
    for (int k = 0; k < 4; ++k)
        g4[k] = make_int4(outv[4 * k], outv[4 * k + 1], outv[4 * k + 2], outv[4 * k + 3]);
}

// ---------- Phase 2: batched gather, 8 independent float4 loads/thread ----------
// Block = 256 thr handles 64 consecutive (b,n) rows (never crosses a batch
// boundary since 4096 % 64 == 0). Thread t: lane = t&31 (float4 within D),
// rsub = t>>5 (row subgroup). 8 indices preloaded -> 8 loads in flight ->
// 8 NT stores. Loads per 32-lane group are 512B contiguous; stores are
// fully contiguous per block.
__global__ __launch_bounds__(256) void ffill_gather(const f4* __restrict__ in,
                                                    const int* __restrict__ gidx,
                                                    f4* __restrict__ out) {
    const int rowblk = blockIdx.x << 6;        // first global row (b*N + n)
    const int tid  = threadIdx.x;
    const int lane = tid & 31;
    const int rsub = tid >> 5;                 // 0..7

    int gi[8];
#pragma unroll
    for (int i = 0; i < 8; ++i) gi[i] = gidx[rowblk + i * 8 + rsub];

    const int bbase = rowblk & ~(FF_N - 1);    // b * N
    f4 v[8];
#pragma unroll
    for (int i = 0; i < 8; ++i)
        v[i] = in[(size_t)(bbase + gi[i]) * (FF_D / 4) + lane];

    const size_t ob = (size_t)rowblk * (FF_D / 4);
#pragma unroll
    for (int i = 0; i < 8; ++i)
        __builtin_nontemporal_store(v[i], &out[ob + i * 256 + tid]);
}

extern "C" void kernel_launch(void* const* d_in, const int* in_sizes, int n_in,
                              void* d_out, int out_size, void* d_ws, size_t ws_size,
                              hipStream_t stream) {
    const float* inp  = (const float*)d_in[0];   // [B, N, D] fp32
    const float* mask = (const float*)d_in[1];   // [B, N]    fp32
    f4* out = (f4*)d_out;

    const int B = in_sizes[1] / FF_N;            // 64
    int* gidx = (int*)d_ws;                      // B*N*4 = 1 MiB scratch

    ffill_scan<<<B, 256, 0, stream>>>(mask, gidx);
    ffill_gather<<<(B * FF_N) / 64, 256, 0, stream>>>((const f4*)inp, gidx, out);
}